// Round 7
// baseline (215.590 us; speedup 1.0000x reference)
//
#include <hip/hip_runtime.h>
#include <stdint.h>

typedef unsigned short u16;
typedef short short8 __attribute__((ext_vector_type(8)));
typedef float f32x4 __attribute__((ext_vector_type(4)));

// ---------- helpers ----------
__device__ __forceinline__ u16 f2bf_fast(float f) {
  union { float f; uint32_t u; } x;
  x.f = f;
  return (u16)((x.u + 0x8000u) >> 16);
}

__device__ __forceinline__ uint32_t pack2bf(float lo, float hi) {
  union { float f; uint32_t u; } a, b;
  a.f = lo; b.f = hi;
  return __builtin_amdgcn_perm(b.u + 0x8000u, a.u + 0x8000u, 0x07060302u);
}

__device__ __forceinline__ float bf2f(uint32_t u) {
  union { uint32_t u; float f; } x;
  x.u = u << 16;
  return x.f;
}

__device__ __forceinline__ void gload_lds16(const void* g, void* l) {
  __builtin_amdgcn_global_load_lds(
      (const __attribute__((address_space(1))) void*)g,
      (__attribute__((address_space(3))) void*)l, 16, 0, 0);
}

__device__ __forceinline__ f32x4 mfma16(short8 a, short8 b, f32x4 c) {
  return __builtin_amdgcn_mfma_f32_16x16x32_bf16(a, b, c, 0, 0, 0);
}

// P32 packed fragment load: granule = ((tile*32+kc)*64+lane)*8 u16
__device__ __forceinline__ short8 ldfrag(const u16* base, int tile, int kc,
                                         int lane) {
  return *(const short8*)(base + ((((tile << 5) + kc) << 6) + lane) * 8);
}

#define QSCALE 0.18033688011112042f

// ---------- pack fp32 -> bf16 P32 fragment layout ----------
__global__ void pack_all(const float* __restrict__ x, const float* __restrict__ wq,
                         const float* __restrict__ wk, const float* __restrict__ wv,
                         const float* __restrict__ wo, u16* __restrict__ xp,
                         u16* __restrict__ wp) {
  const int gi = blockIdx.x * 256 + threadIdx.x;
  const int lane = gi & 63;
  const int kc = (gi >> 6) & 31;
  const int rt = gi >> 11;
  const int col = kc * 32 + (lane >> 4) * 8;
  const float* src;
  int row;
  if (rt < 256) {
    src = x;
    row = rt * 16 + (lane & 15);
  } else {
    const int wti = rt - 256;
    const int widx = wti >> 6;
    src = (widx == 0) ? wq : (widx == 1) ? wk : (widx == 2) ? wv : wo;
    row = (wti & 63) * 16 + (lane & 15);
  }
  const float4* p = (const float4*)(src + (size_t)row * 1024 + col);
  const float4 v0 = p[0], v1 = p[1];
  uint4 o;
  o.x = pack2bf(v0.x, v0.y);
  o.y = pack2bf(v0.z, v0.w);
  o.z = pack2bf(v1.x, v1.y);
  o.w = pack2bf(v1.z, v1.w);
  u16* dst = (rt < 256) ? xp : wp;
  const int og = (rt < 256) ? gi : gi - 524288;
  ((uint4*)dst)[og] = o;
}

// ---------- LDS-free projection GEMM, XCD-partitioned ----------
// xcd = blockIdx.x & 7 owns an L2-resident slab:
//   QK (bidx<64):  bm in [xq*16,+16) (x quarter, 2 MB), bn in [xh*16,+16)
//                  (Wq|Wk half, 2 MB).
//   VT (bidx>=64): bn in [xq*16,+16) (same x rows), bm in [xh*8,+8) (Wv half).
// Block's 4 waves share bn (B-frags hit L1).
__global__ __launch_bounds__(256, 3) void proj_qkv(
    const u16* __restrict__ xp, const u16* __restrict__ wp,
    const float* __restrict__ bq, const float* __restrict__ bk,
    const float* __restrict__ bv, u16* __restrict__ qw, u16* __restrict__ kw,
    u16* __restrict__ vw) {
  const int wv2 = threadIdx.x >> 6;
  const int lane = threadIdx.x & 63;
  const int quad = lane >> 4, l15 = lane & 15;
  const int xcd = blockIdx.x & 7;
  const int bidx = blockIdx.x >> 3;  // 0..95
  const int xq = xcd >> 1, xh = xcd & 1;
  const bool isQK = bidx < 64;
  int at0, bt0, bm, bn;
  const u16 *Ap, *Bp;
  if (isQK) {
    const int q = bidx;
    bn = xh * 16 + (q & 15);
    bm = xq * 16 + (q >> 4) * 4 + wv2;
    Ap = xp; at0 = bm * 4;
    Bp = wp; bt0 = bn * 4;
  } else {
    const int v = bidx - 64;
    bn = xq * 16 + (v & 15);
    bm = xh * 8 + (v >> 4) * 4 + wv2;
    Ap = wp; at0 = 128 + bm * 4;
    Bp = xp; bt0 = bn * 4;
  }

  f32x4 acc[4][4] = {};
  short8 af[2][4], bf[2][4];
#pragma unroll
  for (int mt = 0; mt < 4; ++mt) af[0][mt] = ldfrag(Ap, at0 + mt, 0, lane);
#pragma unroll
  for (int nt = 0; nt < 4; ++nt) bf[0][nt] = ldfrag(Bp, bt0 + nt, 0, lane);

#pragma unroll 4
  for (int kc = 0; kc < 32; ++kc) {
    const int cur = kc & 1, nxt = cur ^ 1;
    if (kc < 31) {
#pragma unroll
      for (int mt = 0; mt < 4; ++mt)
        af[nxt][mt] = ldfrag(Ap, at0 + mt, kc + 1, lane);
#pragma unroll
      for (int nt = 0; nt < 4; ++nt)
        bf[nxt][nt] = ldfrag(Bp, bt0 + nt, kc + 1, lane);
    }
#pragma unroll
    for (int mt = 0; mt < 4; ++mt)
#pragma unroll
      for (int nt = 0; nt < 4; ++nt)
        acc[mt][nt] = mfma16(af[cur][mt], bf[cur][nt], acc[mt][nt]);
  }

#pragma unroll
  for (int nt = 0; nt < 4; ++nt) {
    const int n = bn * 64 + nt * 16 + l15;
#pragma unroll
    for (int mt = 0; mt < 4; ++mt)
#pragma unroll
      for (int r = 0; r < 4; ++r) {
        const int m = bm * 64 + mt * 16 + quad * 4 + r;
        const float a = acc[mt][nt][r];
        if (isQK) {
          const bool isQ = (bn < 16);
          const int nn = isQ ? n : n - 1024;
          const float v = isQ ? (a + bq[nn]) * QSCALE : a + bk[nn];
          u16* op = isQ ? qw : kw;
          const int b = m >> 11, s = m & 2047, hh = nn >> 6, d = nn & 63;
          op[((size_t)((b * 16 + hh) * 2048 + s)) * 64 + d] = f2bf_fast(v);
        } else {
          const float v = a + bv[m];
          const int b = n >> 11, s = n & 2047;
          vw[((size_t)(b * 1024 + m)) * 2048 + s] = f2bf_fast(v);
        }
      }
  }
}

// ---------- flash attention: transposed, key-split, K=32 PV ----------
// S^T = K @ Q^T with A-rows fed through sigma (bit2<->bit3 of l15) so each
// quad's C-regs hold an aligned 4-key run; one shfl_xor(32) assembles the
// 8-key K=32 B-operand. O^T += V^T @ P^T with conflict-free b128 V reads.
__global__ __launch_bounds__(256) void attn_kernel(
    const u16* __restrict__ Q, const u16* __restrict__ Kt,
    const u16* __restrict__ Vt, u16* __restrict__ op0, u16* __restrict__ op1,
    float* __restrict__ lp) {
  __shared__ __align__(16) u16 Sm[16384];  // 32 KB
  const int tid = threadIdx.x, lane = tid & 63, w = tid >> 6;
  const int quad = lane >> 4, l15 = lane & 15;
  const int qt = blockIdx.x;
  const int bh = blockIdx.y >> 1;
  const int ks = blockIdx.y & 1;
  // sigma: swap bits 2 and 3 of l15
  const int sl = (l15 & 3) | ((l15 >> 1) & 4) | ((l15 << 1) & 8);

  const char* Qb = (const char*)(Q + ((size_t)bh * 2048 + qt * 128) * 64);
  const char* Kb = (const char*)(Kt + ((size_t)bh * 2048 + ks * 1024) * 64);
  const char* Vb = (const char*)(Vt + (size_t)bh * 64 * 2048 + ks * 1024);

  auto stageKV = [&](int kt, int b) {
    u16* Kl = Sm + b * 4096;
    u16* Vl = Sm + 8192 + b * 4096;
#pragma unroll
    for (int i = 0; i < 2; ++i) {
      const int G = (w * 2 + i) * 64 + lane;
      const int r = G >> 3, slw = G & 7;
      gload_lds16(Kb + (size_t)(kt * 64 + r) * 128 + ((slw ^ (r & 7)) * 16),
                  &Kl[G * 8]);
      gload_lds16(Vb + (size_t)r * 4096 + kt * 128 + ((slw ^ (r & 7)) * 16),
                  &Vl[G * 8]);
    }
  };

#pragma unroll
  for (int i = 0; i < 4; ++i) {
    const int G = (w * 4 + i) * 64 + lane;
    const int row = G >> 3, slw = G & 7;
    u16* qdst = (G < 512) ? (Sm + 4096) : (Sm + 12288);
    gload_lds16(Qb + (size_t)row * 128 + ((slw ^ (row & 7)) * 16),
                &qdst[(G & 511) * 8]);
  }
  stageKV(0, 0);
  __syncthreads();

  const u16* qreg = (w < 2) ? (Sm + 4096) : (Sm + 12288);
  const int qr0 = (w & 1) * 32;
  short8 aq[2][2];
#pragma unroll
  for (int mt = 0; mt < 2; ++mt)
#pragma unroll
    for (int kc = 0; kc < 2; ++kc)
      aq[mt][kc] = *(const short8*)&qreg[(qr0 + mt * 16 + l15) * 64 +
                                         (((kc * 4 + quad) ^ (l15 & 7)) * 8)];
  __syncthreads();

  f32x4 ot[4][2] = {};
  float lsum[2] = {};

  for (int kt = 0; kt < 16; ++kt) {
    const int buf = kt & 1;
    if (kt < 15) stageKV(kt + 1, buf ^ 1);
    const u16* Kl = Sm + buf * 4096;
    const u16* Vl = Sm + 8192 + buf * 4096;

    // S^T = K @ Q^T, A-rows permuted by sigma:
    // C entry (quad,r) of tile ntk = key ntk*16 + sigma(quad*4+r)
    f32x4 st[2][4] = {};
#pragma unroll
    for (int kc = 0; kc < 2; ++kc)
#pragma unroll
      for (int ntk = 0; ntk < 4; ++ntk) {
        short8 kf = *(const short8*)&Kl[(ntk * 16 + sl) * 64 +
                                        (((kc * 4 + quad) ^ (sl & 7)) * 8)];
        st[0][ntk] = mfma16(kf, aq[0][kc], st[0][ntk]);
        st[1][ntk] = mfma16(kf, aq[1][kc], st[1][ntk]);
      }

    // exp2 + pack: tile ntk regs hold keys base + quad-run of 4
    uint2 pp[2][4];
#pragma unroll
    for (int mt = 0; mt < 2; ++mt)
#pragma unroll
      for (int ntk = 0; ntk < 4; ++ntk) {
        const float e0 = __builtin_amdgcn_exp2f(st[mt][ntk][0]);
        const float e1 = __builtin_amdgcn_exp2f(st[mt][ntk][1]);
        const float e2 = __builtin_amdgcn_exp2f(st[mt][ntk][2]);
        const float e3 = __builtin_amdgcn_exp2f(st[mt][ntk][3]);
        lsum[mt] += (e0 + e1) + (e2 + e3);
        pp[mt][ntk].x = pack2bf(e0, e1);
        pp[mt][ntk].y = pack2bf(e2, e3);
      }

    // assemble K=32 B-operands: group g uses tiles 2g, 2g+1;
    // quads 0,1 <- tile 2g (own||xchg), quads 2,3 <- tile 2g+1 (xchg||own)
    short8 pf[2][2];
#pragma unroll
    for (int mt = 0; mt < 2; ++mt)
#pragma unroll
      for (int g = 0; g < 2; ++g) {
        const uint2 o0 = pp[mt][2 * g], o1 = pp[mt][2 * g + 1];
        const uint32_t x0l = __shfl_xor(o0.x, 32), x0h = __shfl_xor(o0.y, 32);
        const uint32_t x1l = __shfl_xor(o1.x, 32), x1h = __shfl_xor(o1.y, 32);
        union { uint32_t u[4]; short8 s; } f;
        if (quad < 2) {
          f.u[0] = o0.x; f.u[1] = o0.y; f.u[2] = x0l; f.u[3] = x0h;
        } else {
          f.u[0] = x1l; f.u[1] = x1h; f.u[2] = o1.x; f.u[3] = o1.y;
        }
        pf[mt][g] = f.s;
      }

    // O^T += V^T @ P^T : b128 V A-frags (keys 32g+quad*8..+7), conflict-free
#pragma unroll
    for (int g = 0; g < 2; ++g)
#pragma unroll
      for (int ntd = 0; ntd < 4; ++ntd) {
        short8 vf = *(const short8*)&Vl[(ntd * 16 + l15) * 64 +
                                        (((g * 4 + quad) ^ (l15 & 7)) * 8)];
        ot[ntd][0] = mfma16(vf, pf[0][g], ot[ntd][0]);
        ot[ntd][1] = mfma16(vf, pf[1][g], ot[ntd][1]);
      }
    if (kt < 15) __syncthreads();
  }

  // epilogue: packed o-partials + l-partials
  const int b = bh >> 4, h = bh & 15;
  u16* op = ks ? op1 : op0;
#pragma unroll
  for (int mt = 0; mt < 2; ++mt) {
    float l = lsum[mt];
    l += __shfl_xor(l, 16);
    l += __shfl_xor(l, 32);
    const int srow = qt * 128 + w * 32 + mt * 16 + l15;
    if (quad == 0) lp[((size_t)(ks * 32 + bh)) * 2048 + srow] = l;
    const int rt = b * 128 + qt * 8 + w * 2 + mt;
#pragma unroll
    for (int ntd = 0; ntd < 4; ++ntd) {
      const int kc = h * 2 + (ntd >> 1);
      const int lnq = ((ntd & 1) * 2 + (quad >> 1)) & 3;
      const int j0 = (quad & 1) * 4;
      uint2 ov;
      ov.x = pack2bf(ot[ntd][mt][0], ot[ntd][mt][1]);
      ov.y = pack2bf(ot[ntd][mt][2], ot[ntd][mt][3]);
      *(uint2*)(op + ((size_t)((rt * 32 + kc) * 64 + lnq * 16 + l15)) * 8 + j0) = ov;
    }
  }
}

// ---------- combine (packed granule-wise): awp = (o0+o1)/(l0+l1) ----------
__global__ void attn_combine(const u16* __restrict__ op0,
                             const u16* __restrict__ op1,
                             const float* __restrict__ lp,
                             u16* __restrict__ awp) {
  const int g = blockIdx.x * 256 + threadIdx.x;
  const int ln = g & 63;
  const int kc = (g >> 6) & 31;
  const int rt = g >> 11;
  const int row = rt * 16 + (ln & 15);
  const int b = row >> 11, s = row & 2047;
  const int h = kc >> 1;
  const int lidx = (b * 16 + h) * 2048 + s;
  const float inv = __builtin_amdgcn_rcpf(lp[lidx] + lp[lidx + 65536]);
  const uint4 a0 = ((const uint4*)op0)[g];
  const uint4 a1 = ((const uint4*)op1)[g];
  uint4 o;
  o.x = pack2bf((bf2f(a0.x) + bf2f(a1.x)) * inv,
                (bf2f(a0.x >> 16) + bf2f(a1.x >> 16)) * inv);
  o.y = pack2bf((bf2f(a0.y) + bf2f(a1.y)) * inv,
                (bf2f(a0.y >> 16) + bf2f(a1.y >> 16)) * inv);
  o.z = pack2bf((bf2f(a0.z) + bf2f(a1.z)) * inv,
                (bf2f(a0.z >> 16) + bf2f(a1.z >> 16)) * inv);
  o.w = pack2bf((bf2f(a0.w) + bf2f(a1.w)) * inv,
                (bf2f(a0.w >> 16) + bf2f(a1.w >> 16)) * inv);
  ((uint4*)awp)[g] = o;
}

// ---------- LDS-free out projection, XCD-partitioned ----------
__global__ __launch_bounds__(256, 3) void out_proj(const u16* __restrict__ awp,
                                                   const u16* __restrict__ wp,
                                                   const float* __restrict__ bo,
                                                   float* __restrict__ out) {
  const int wv2 = threadIdx.x >> 6;
  const int lane = threadIdx.x & 63;
  const int quad = lane >> 4, l15 = lane & 15;
  const int xcd = blockIdx.x & 7;
  const int bidx = blockIdx.x >> 3;  // 0..63
  const int xq = xcd >> 1, xh = xcd & 1;
  const int bnn = xh * 16 + (bidx & 15);
  const int bm = xq * 16 + (bidx >> 4) * 4 + wv2;
  const int at0 = bm * 4, bt0 = 192 + bnn * 2;

  f32x4 acc[4][2] = {};
  short8 af[2][4], bf[2][2];
#pragma unroll
  for (int mt = 0; mt < 4; ++mt) af[0][mt] = ldfrag(awp, at0 + mt, 0, lane);
#pragma unroll
  for (int nt = 0; nt < 2; ++nt) bf[0][nt] = ldfrag(wp, bt0 + nt, 0, lane);

#pragma unroll 4
  for (int kc = 0; kc < 32; ++kc) {
    const int cur = kc & 1, nxt = cur ^ 1;
    if (kc < 31) {
#pragma unroll
      for (int mt = 0; mt < 4; ++mt)
        af[nxt][mt] = ldfrag(awp, at0 + mt, kc + 1, lane);
#pragma unroll
      for (int nt = 0; nt < 2; ++nt)
        bf[nxt][nt] = ldfrag(wp, bt0 + nt, kc + 1, lane);
    }
#pragma unroll
    for (int mt = 0; mt < 4; ++mt)
#pragma unroll
      for (int nt = 0; nt < 2; ++nt)
        acc[mt][nt] = mfma16(af[cur][mt], bf[cur][nt], acc[mt][nt]);
  }

#pragma unroll
  for (int nt = 0; nt < 2; ++nt) {
    const int n = bnn * 32 + nt * 16 + l15;
    const float bb = bo[n];
#pragma unroll
    for (int mt = 0; mt < 4; ++mt)
#pragma unroll
      for (int r = 0; r < 4; ++r) {
        const int m = bm * 64 + mt * 16 + quad * 4 + r;
        out[(size_t)m * 1024 + n] = acc[mt][nt][r] + bb;
      }
  }
}

// ---------- launch ----------
extern "C" void kernel_launch(void* const* d_in, const int* in_sizes, int n_in,
                              void* d_out, int out_size, void* d_ws, size_t ws_size,
                              hipStream_t stream) {
  const float* x  = (const float*)d_in[0];
  const float* Wq = (const float*)d_in[1];
  const float* bq = (const float*)d_in[2];
  const float* Wk = (const float*)d_in[3];
  const float* bk = (const float*)d_in[4];
  const float* Wv = (const float*)d_in[5];
  const float* bv = (const float*)d_in[6];
  const float* Wo = (const float*)d_in[7];
  const float* bo = (const float*)d_in[8];

  const size_t M4 = (size_t)4 * 1024 * 1024;
  u16* xp  = (u16*)d_ws;
  u16* wp  = xp + M4;
  u16* qw  = wp + M4;
  u16* kw  = qw + M4;
  u16* vw  = kw + M4;
  u16* op1 = vw + M4;
  u16* awp = op1 + M4;
  float* lp = (float*)(awp + M4);
  u16* op0 = xp;

  pack_all<<<4096, 256, 0, stream>>>(x, Wq, Wk, Wv, Wo, xp, wp);

  proj_qkv<<<768, 256, 0, stream>>>(xp, wp, bq, bk, bv, qw, kw, vw);

  attn_kernel<<<dim3(16, 64), 256, 0, stream>>>(qw, kw, vw, op0, op1, lp);

  attn_combine<<<2048, 256, 0, stream>>>(op0, op1, lp, awp);

  out_proj<<<512, 256, 0, stream>>>(awp, wp, bo, (float*)d_out);
}